// Round 9
// baseline (264.501 us; speedup 1.0000x reference)
//
#include <hip/hip_runtime.h>

typedef _Float16 h8_t __attribute__((ext_vector_type(8)));
typedef _Float16 h4_t __attribute__((ext_vector_type(4)));
typedef float f32x4 __attribute__((ext_vector_type(4)));

#define NB 64
#define NH 8
#define NL 2048
#define ND 512
// flat K matrix rows: NB*NL = 131072

#define SBAR() __builtin_amdgcn_sched_barrier(0)

// swizzled half-index into a [rows][32]-fp16 tile: XOR 16B-chunk with row bits
__device__ __forceinline__ int swz_idx(int row, int chunk) {
    return row * 32 + ((chunk ^ ((row >> 1) & 3)) << 3);
}

// ---------------- Kernel 1: Wq = Q @ Ww.T + Wb  (f32, tiny) ----------------
__global__ __launch_bounds__(256) void wq_kernel(const float* __restrict__ Q,
                                                 const float* __restrict__ Ww,
                                                 const float* __restrict__ Wb,
                                                 float* __restrict__ Wq) {
    __shared__ float q[ND];
    const int b = blockIdx.x;
    const int t = threadIdx.x;
    for (int i = t; i < ND; i += 256) q[i] = Q[b * ND + i];
    __syncthreads();
    for (int j = t; j < ND; j += 256) {
        const float* wr = Ww + (size_t)j * ND;
        float acc = 0.f;
        for (int k = 0; k < ND; k += 4) {
            float4 w = *(const float4*)(wr + k);
            acc += q[k] * w.x + q[k + 1] * w.y + q[k + 2] * w.z + q[k + 3] * w.w;
        }
        Wq[b * ND + j] = acc + Wb[j];
    }
}

// ---------------- Kernel 2: convert Uw (f32) -> fp16 (RNE) ----------------
__global__ __launch_bounds__(256) void cvt_uw_kernel(const float* __restrict__ Uw,
                                                     _Float16* __restrict__ UwH) {
    const size_t i = ((size_t)blockIdx.x * 256 + threadIdx.x) * 4;
    float4 v = *(const float4*)(Uw + i);
    h4_t h = {(_Float16)v.x, (_Float16)v.y, (_Float16)v.z, (_Float16)v.w};
    *(h4_t*)(UwH + i) = h;
}

// ---------------- Kernel 3: Uk GEMM (fp16 MFMA) + tanh-reduce -> scores ----------------
// LDS-traffic-minimized design: B NEVER touches LDS (per-lane fragment loads from
// L2-resident 512KB UwH, depth-1 reg prefetch). Only A is LDS-staged (single 8KB
// buffer, f32->fp16 cvt, XOR-swizzled). BM=128, BN=128, BK=32, 4 waves (2m x 2n),
// 256 threads, 3 blocks/CU via __launch_bounds__(256,3).
// Raw s_barrier + lgkmcnt(0) only -- compiler inserts counted vmcnt for reg deps.
__global__ __launch_bounds__(256, 3) void uk_score_kernel(
    const float* __restrict__ Km,       // [131072][512] f32
    const _Float16* __restrict__ UwH,   // [512][512] fp16
    const float* __restrict__ Ub,       // [512]
    const float* __restrict__ Wq,       // [64][512]
    const float* __restrict__ Vw,       // [64]
    const float* __restrict__ Vb,       // [1]
    float* __restrict__ scores)         // [512][2048]
{
    __shared__ __align__(16) _Float16 Al[128 * 32];   // 8 KB, single buffer

    const int t = threadIdx.x;
    const int lane = t & 63;
    const int wave = t >> 6;          // 0..3
    const int wm = wave >> 1;         // 0..1
    const int wn = wave & 1;          // 0..1
    const int col16 = lane & 15;
    const int kg = lane >> 4;         // 0..3

    const int bid = blockIdx.x;                      // 4096 blocks
    const int swz = (bid & 7) * 512 + (bid >> 3);    // bijective; 4 n-twins adjacent per XCD
    const int tn = swz & 3;
    const int tm = swz >> 2;                         // 0..1023
    const size_t row0 = (size_t)tm * 128;
    const int n0 = tn * 128;

    // A staging: thread t covers row (t>>1), half-row (t&1) -> 16 floats/step
    const int arow = t >> 1;
    const int ah = t & 1;
    const float* gA = Km + (row0 + arow) * (size_t)ND + ah * 16;
    const int adst0 = swz_idx(arow, ah * 2);
    const int adst1 = swz_idx(arow, ah * 2 + 1);

    // B fragment pointers (per-lane; k-contiguous rows of UwH; L2-resident)
    const _Float16* gB[4];
#pragma unroll
    for (int j = 0; j < 4; ++j)
        gB[j] = UwH + (size_t)(n0 + wn * 64 + j * 16 + col16) * ND + kg * 8;

    f32x4 acc[4][4];
#pragma unroll
    for (int i = 0; i < 4; ++i)
#pragma unroll
        for (int j = 0; j < 4; ++j) acc[i][j] = (f32x4){0.f, 0.f, 0.f, 0.f};

    float4 ra0[4], ra1[4];   // A reg slots: slot[s&1] holds A(s+2) after issue at step s
    h8_t bf[4];

    // ---- prologue: A(0)->ra0, A(1)->ra1, B(0)->bf, cvt A(0) -> Al ----
#pragma unroll
    for (int q = 0; q < 4; ++q) ra0[q] = *(const float4*)(gA + q * 4);
#pragma unroll
    for (int q = 0; q < 4; ++q) ra1[q] = *(const float4*)(gA + 32 + q * 4);
#pragma unroll
    for (int j = 0; j < 4; ++j) bf[j] = *(const h8_t*)(gB[j]);
    {
        h8_t h0 = {(_Float16)ra0[0].x, (_Float16)ra0[0].y, (_Float16)ra0[0].z, (_Float16)ra0[0].w,
                   (_Float16)ra0[1].x, (_Float16)ra0[1].y, (_Float16)ra0[1].z, (_Float16)ra0[1].w};
        h8_t h1 = {(_Float16)ra0[2].x, (_Float16)ra0[2].y, (_Float16)ra0[2].z, (_Float16)ra0[2].w,
                   (_Float16)ra0[3].x, (_Float16)ra0[3].y, (_Float16)ra0[3].z, (_Float16)ra0[3].w};
        *(h8_t*)&Al[adst0] = h0;
        *(h8_t*)&Al[adst1] = h1;
    }

#pragma unroll
    for (int s = 0; s < 16; ++s) {
        // barrier 1: Al now holds A(s) (my ds_write drained first)
        asm volatile("s_waitcnt lgkmcnt(0)" ::: "memory");
        SBAR();
        __builtin_amdgcn_s_barrier();
        SBAR();
        // issue A(s+2) f32 loads into free slot (consumed by cvt at step s-1)
        if (s <= 13) {
            if (s & 1) {
#pragma unroll
                for (int q = 0; q < 4; ++q) ra1[q] = *(const float4*)(gA + (s + 2) * 32 + q * 4);
            } else {
#pragma unroll
                for (int q = 0; q < 4; ++q) ra0[q] = *(const float4*)(gA + (s + 2) * 32 + q * 4);
            }
        }
        SBAR();
        // A fragments from LDS (conflict-free swizzled)
        h8_t af[4];
#pragma unroll
        for (int i = 0; i < 4; ++i)
            af[i] = *(const h8_t*)&Al[swz_idx(wm * 64 + i * 16 + col16, kg)];
        asm volatile("s_waitcnt lgkmcnt(0)" ::: "memory");
        SBAR();
        __builtin_amdgcn_s_setprio(1);
#pragma unroll
        for (int i = 0; i < 4; ++i)
#pragma unroll
            for (int j = 0; j < 4; ++j)
                acc[i][j] = __builtin_amdgcn_mfma_f32_16x16x32_f16(af[i], bf[j], acc[i][j], 0, 0, 0);
        __builtin_amdgcn_s_setprio(0);
        SBAR();
        // B(s+1) fragment loads (bf(s) just consumed; ~1 step of L2 cover)
        if (s <= 14) {
#pragma unroll
            for (int j = 0; j < 4; ++j) bf[j] = *(const h8_t*)(gB[j] + (s + 1) * 32);
        }
        SBAR();
        if (s <= 14) {
            // barrier 2: all waves done reading Al(s); then overwrite with A(s+1)
            __builtin_amdgcn_s_barrier();
            SBAR();
            if (s & 1) {
                h8_t h0 = {(_Float16)ra0[0].x, (_Float16)ra0[0].y, (_Float16)ra0[0].z, (_Float16)ra0[0].w,
                           (_Float16)ra0[1].x, (_Float16)ra0[1].y, (_Float16)ra0[1].z, (_Float16)ra0[1].w};
                h8_t h1 = {(_Float16)ra0[2].x, (_Float16)ra0[2].y, (_Float16)ra0[2].z, (_Float16)ra0[2].w,
                           (_Float16)ra0[3].x, (_Float16)ra0[3].y, (_Float16)ra0[3].z, (_Float16)ra0[3].w};
                *(h8_t*)&Al[adst0] = h0;
                *(h8_t*)&Al[adst1] = h1;
            } else {
                h8_t h0 = {(_Float16)ra1[0].x, (_Float16)ra1[0].y, (_Float16)ra1[0].z, (_Float16)ra1[0].w,
                           (_Float16)ra1[1].x, (_Float16)ra1[1].y, (_Float16)ra1[1].z, (_Float16)ra1[1].w};
                h8_t h1 = {(_Float16)ra1[2].x, (_Float16)ra1[2].y, (_Float16)ra1[2].z, (_Float16)ra1[2].w,
                           (_Float16)ra1[3].x, (_Float16)ra1[3].y, (_Float16)ra1[3].z, (_Float16)ra1[3].w};
                *(h8_t*)&Al[adst0] = h0;
                *(h8_t*)&Al[adst1] = h1;
            }
            SBAR();
        }
    }

    // epilogue: score(row, jb) = sum_dh tanh(Uk + Wq + Ub) * Vw  (+Vb)
    const int b = (int)(row0 >> 11);
    const int h = ((int)row0 >> 8) & 7;
    const int i256b = (int)row0 & 255;

    float vw[4], wqv[4], ubv[4];
#pragma unroll
    for (int j = 0; j < 4; ++j) {
        const int jglob = n0 + wn * 64 + j * 16 + col16;  // 0..511
        const int dh = jglob & 63;
        vw[j] = Vw[dh];
        wqv[j] = Wq[b * ND + h * 64 + dh];
        ubv[j] = Ub[jglob];
    }
    const float vb0 = Vb[0];
    const int jb = tn * 2 + wn;       // 0..7
    const int bh = b * 8 + h;

#pragma unroll
    for (int i = 0; i < 4; ++i) {
#pragma unroll
        for (int r = 0; r < 4; ++r) {
            float s = 0.f;
#pragma unroll
            for (int j = 0; j < 4; ++j) {
                float x = acc[i][j][r] + wqv[j] + ubv[j];
                x = fminf(fmaxf(x, -15.f), 15.f);
                float e = __expf(2.f * x);
                s += ((e - 1.f) / (e + 1.f)) * vw[j];
            }
#pragma unroll
            for (int o = 8; o >= 1; o >>= 1) s += __shfl_xor(s, o);
            if (col16 == 0) {
                const int rloc = wm * 64 + i * 16 + kg * 4 + r;
                const int m = (i256b + rloc) * 8 + jb;
                scores[(size_t)bh * NL + m] = s + vb0;
            }
        }
    }
}

// ---------------- Kernel 4: softmax -> dist (out) + attn = dist @ Kh ----------------
__global__ __launch_bounds__(256) void softmax_attn_kernel(
    const float* __restrict__ Km,
    const float* __restrict__ scores,
    float* __restrict__ out)  // [0,32768) attn, [32768,...) dist
{
    __shared__ float sd[NL];
    __shared__ float red[256];
    __shared__ float att[16][64];

    const int bh = blockIdx.x;
    const int b = bh >> 3, h = bh & 7;
    const int t = threadIdx.x;

    float loc[8];
    float mx = -1e30f;
#pragma unroll
    for (int j = 0; j < 8; ++j) {
        loc[j] = scores[(size_t)bh * NL + j * 256 + t];
        mx = fmaxf(mx, loc[j]);
    }
    red[t] = mx;
    __syncthreads();
    for (int s2 = 128; s2 > 0; s2 >>= 1) {
        if (t < s2) red[t] = fmaxf(red[t], red[t + s2]);
        __syncthreads();
    }
    mx = red[0];
    __syncthreads();
    float sum = 0.f;
#pragma unroll
    for (int j = 0; j < 8; ++j) {
        loc[j] = __expf(loc[j] - mx);
        sum += loc[j];
    }
    red[t] = sum;
    __syncthreads();
    for (int s2 = 128; s2 > 0; s2 >>= 1) {
        if (t < s2) red[t] += red[t + s2];
        __syncthreads();
    }
    const float inv = 1.f / red[0];
    __syncthreads();

    float* dist_out = out + 32768 + (size_t)bh * NL;
#pragma unroll
    for (int j = 0; j < 8; ++j) {
        float d = loc[j] * inv;
        sd[j * 256 + t] = d;
        dist_out[j * 256 + t] = d;
    }
    __syncthreads();

    const int wave = t >> 6, lane = t & 63;
    const int g = lane >> 4;
    const int c4 = (lane & 15) * 4;
    f32x4 acc = (f32x4){0.f, 0.f, 0.f, 0.f};
    const float* kb = Km + ((size_t)b * NL + h * 256) * ND;
    for (int rr = 0; rr < 16; ++rr) {
        const int row = wave * 64 + rr * 4 + g;
        const float* kr = kb + (size_t)row * ND;
#pragma unroll
        for (int jb2 = 0; jb2 < 8; ++jb2) {
            const float w = sd[row * 8 + jb2];
            float4 v = *(const float4*)(kr + jb2 * 64 + c4);
            acc[0] += w * v.x;
            acc[1] += w * v.y;
            acc[2] += w * v.z;
            acc[3] += w * v.w;
        }
    }
    *(f32x4*)&att[wave * 4 + g][c4] = acc;
    __syncthreads();
    if (t < 64) {
        float a = 0.f;
#pragma unroll
        for (int i = 0; i < 16; ++i) a += att[i][t];
        out[(size_t)b * ND + h * 64 + t] = a;
    }
}

extern "C" void kernel_launch(void* const* d_in, const int* in_sizes, int n_in,
                              void* d_out, int out_size, void* d_ws, size_t ws_size,
                              hipStream_t stream) {
    const float* Q  = (const float*)d_in[0];
    const float* Km = (const float*)d_in[1];
    const float* Ww = (const float*)d_in[2];
    const float* Wb = (const float*)d_in[3];
    const float* Uw = (const float*)d_in[4];
    const float* Ub = (const float*)d_in[5];
    const float* Vw = (const float*)d_in[6];
    const float* Vb = (const float*)d_in[7];
    float* out = (float*)d_out;

    char* ws = (char*)d_ws;
    float* scores = (float*)ws;                              // 4 MB
    float* Wq = (float*)(ws + 4194304);                      // 128 KB
    _Float16* UwH = (_Float16*)(ws + 4194304 + 131072);      // 512 KB

    wq_kernel<<<dim3(64), dim3(256), 0, stream>>>(Q, Ww, Wb, Wq);
    cvt_uw_kernel<<<dim3(256), dim3(256), 0, stream>>>(Uw, UwH);
    uk_score_kernel<<<dim3(4096), dim3(256), 0, stream>>>(Km, UwH, Ub, Wq, Vw, Vb, scores);
    softmax_attn_kernel<<<dim3(512), dim3(256), 0, stream>>>(Km, scores, out);
}

// Round 10
// 251.769 us; speedup vs baseline: 1.0506x; 1.0506x over previous
//
#include <hip/hip_runtime.h>

typedef _Float16 h8_t __attribute__((ext_vector_type(8)));
typedef _Float16 h4_t __attribute__((ext_vector_type(4)));
typedef float f32x4 __attribute__((ext_vector_type(4)));

#define NB 64
#define NH 8
#define NL 2048
#define ND 512
// flat K matrix rows: NB*NL = 131072

#define GLD_LDS16(g, l) \
    __builtin_amdgcn_global_load_lds((const __attribute__((address_space(1))) unsigned int*)(g), \
                                     (__attribute__((address_space(3))) unsigned int*)(l), 16, 0, 0)

// swizzled half-index into a [rows][32]-fp16 tile: XOR 16B-chunk with row bits
__device__ __forceinline__ int swz_idx(int row, int chunk) {
    return row * 32 + ((chunk ^ ((row >> 1) & 3)) << 3);
}

// ---------------- Kernel 1: Wq = Q @ Ww.T + Wb  (f32, tiny) ----------------
__global__ __launch_bounds__(256) void wq_kernel(const float* __restrict__ Q,
                                                 const float* __restrict__ Ww,
                                                 const float* __restrict__ Wb,
                                                 float* __restrict__ Wq) {
    __shared__ float q[ND];
    const int b = blockIdx.x;
    const int t = threadIdx.x;
    for (int i = t; i < ND; i += 256) q[i] = Q[b * ND + i];
    __syncthreads();
    for (int j = t; j < ND; j += 256) {
        const float* wr = Ww + (size_t)j * ND;
        float acc = 0.f;
        for (int k = 0; k < ND; k += 4) {
            float4 w = *(const float4*)(wr + k);
            acc += q[k] * w.x + q[k + 1] * w.y + q[k + 2] * w.z + q[k + 3] * w.w;
        }
        Wq[b * ND + j] = acc + Wb[j];
    }
}

// ---------------- Kernel 2: convert Uw (f32) -> fp16 (RNE) ----------------
__global__ __launch_bounds__(256) void cvt_uw_kernel(const float* __restrict__ Uw,
                                                     _Float16* __restrict__ UwH) {
    const size_t i = ((size_t)blockIdx.x * 256 + threadIdx.x) * 4;
    float4 v = *(const float4*)(Uw + i);
    h4_t h = {(_Float16)v.x, (_Float16)v.y, (_Float16)v.z, (_Float16)v.w};
    *(h4_t*)(UwH + i) = h;
}

// ---------------- Kernel 3: Uk GEMM (fp16 MFMA) + tanh-reduce -> scores ----------------
// EXACT R2 loop structure (champion, 164us), halved block for occupancy:
// BM=128, BN=128, BK=32, 4 waves (2m x 2n), 16 KB LDS, launch_bounds(256,4)
// -> 4 resident blocks/CU (16 waves): de-phased convoys fill the LDS-port /
// MFMA gaps that capped the 8-wave version at 2 blocks/CU.
__global__ __launch_bounds__(256, 4) void uk_score_kernel(
    const float* __restrict__ Km,       // [131072][512] f32
    const _Float16* __restrict__ UwH,   // [512][512] fp16
    const float* __restrict__ Ub,       // [512]
    const float* __restrict__ Wq,       // [64][512]
    const float* __restrict__ Vw,       // [64]
    const float* __restrict__ Vb,       // [1]
    float* __restrict__ scores)         // [512][2048]
{
    __shared__ __align__(16) _Float16 Al[128 * 32];   // 8 KB
    __shared__ __align__(16) _Float16 Bl[128 * 32];   // 8 KB

    const int t = threadIdx.x;
    const int lane = t & 63;
    const int wave = t >> 6;          // 0..3
    const int wm = wave >> 1;         // 0..1
    const int wn = wave & 1;          // 0..1

    // XCD swizzle: bids {8k+x} -> XCD x, k consecutive; k=0..3 are the 4 n-twins
    // of one m-panel (tm = 128x + k>>2 ... i.e. same tm for k%4) -> A L2-hot.
    const int bid = blockIdx.x;                      // 4096 blocks
    const int swz = (bid & 7) * 512 + (bid >> 3);    // bijective
    const int tn = swz & 3;
    const int tm = swz >> 2;                         // 0..1023
    const size_t row0 = (size_t)tm * 128;
    const int n0 = tn * 128;

    f32x4 acc[4][4];
#pragma unroll
    for (int i = 0; i < 4; ++i)
#pragma unroll
        for (int j = 0; j < 4; ++j) acc[i][j] = (f32x4){0.f, 0.f, 0.f, 0.f};

    // A staging: thread t loads 16 consecutive floats of row (t>>1), half (t&1)
    const int arow = t >> 1;          // 0..127
    const int ahf = t & 1;
    const float* gA = Km + (row0 + arow) * (size_t)ND + ahf * 16;
    const int adst0 = swz_idx(arow, ahf * 2);
    const int adst1 = swz_idx(arow, ahf * 2 + 1);

    // B staging (global_load_lds, source pre-swizzled): slot = it*256 + t
    const int brow0 = t >> 2;                       // it=0: rows 0..63
    const int bc0 = (t & 3) ^ ((brow0 >> 1) & 3);
    const int brow1 = (256 + t) >> 2;               // it=1: rows 64..127
    const int bc1 = (t & 3) ^ ((brow1 >> 1) & 3);
    const _Float16* gB0 = UwH + (size_t)(n0 + brow0) * ND + bc0 * 8;
    const _Float16* gB1 = UwH + (size_t)(n0 + brow1) * ND + bc1 * 8;
    const int bdst0 = (t & ~63) * 16;               // byte offsets within Bl
    const int bdst1 = (256 + (t & ~63)) * 16;

    const int col16 = lane & 15;
    const int kg = lane >> 4;

    for (int kk = 0; kk < ND; kk += 32) {
        // A: global f32 -> regs (issued before barrier; latency overlaps prev compute)
        const float4 v0 = *(const float4*)(gA + kk);
        const float4 v1 = *(const float4*)(gA + kk + 4);
        const float4 v2 = *(const float4*)(gA + kk + 8);
        const float4 v3 = *(const float4*)(gA + kk + 12);
        __syncthreads();   // previous tile fully consumed
        // B: direct-to-LDS DMA, source pre-swizzled so LDS lands XOR-swizzled
        GLD_LDS16(gB0 + kk, (char*)Bl + bdst0);
        GLD_LDS16(gB1 + kk, (char*)Bl + bdst1);
        // A: cvt (RNE) + two swizzled ds_write_b128
        h8_t h0 = {(_Float16)v0.x, (_Float16)v0.y, (_Float16)v0.z, (_Float16)v0.w,
                   (_Float16)v1.x, (_Float16)v1.y, (_Float16)v1.z, (_Float16)v1.w};
        h8_t h1 = {(_Float16)v2.x, (_Float16)v2.y, (_Float16)v2.z, (_Float16)v2.w,
                   (_Float16)v3.x, (_Float16)v3.y, (_Float16)v3.z, (_Float16)v3.w};
        *(h8_t*)&Al[adst0] = h0;
        *(h8_t*)&Al[adst1] = h1;
        __syncthreads();   // drains gload_lds + ds_write

        h8_t af[4], bf[4];
#pragma unroll
        for (int i = 0; i < 4; ++i)
            af[i] = *(const h8_t*)&Al[swz_idx(wm * 64 + i * 16 + col16, kg)];
#pragma unroll
        for (int j = 0; j < 4; ++j)
            bf[j] = *(const h8_t*)&Bl[swz_idx(wn * 64 + j * 16 + col16, kg)];
#pragma unroll
        for (int i = 0; i < 4; ++i)
#pragma unroll
            for (int j = 0; j < 4; ++j)
                acc[i][j] = __builtin_amdgcn_mfma_f32_16x16x32_f16(af[i], bf[j], acc[i][j], 0, 0, 0);
    }

    // epilogue: score(row, jb) = sum_dh tanh(Uk + Wq + Ub) * Vw  (+Vb)
    const int b = (int)(row0 >> 11);
    const int h = ((int)row0 >> 8) & 7;
    const int i256b = (int)row0 & 255;

    float vw[4], wqv[4], ubv[4];
#pragma unroll
    for (int j = 0; j < 4; ++j) {
        const int jglob = n0 + wn * 64 + j * 16 + col16;  // 0..511
        const int dh = jglob & 63;
        vw[j] = Vw[dh];
        wqv[j] = Wq[b * ND + h * 64 + dh];
        ubv[j] = Ub[jglob];
    }
    const float vb0 = Vb[0];
    const int jb = tn * 2 + wn;       // 0..7
    const int bh = b * 8 + h;

#pragma unroll
    for (int i = 0; i < 4; ++i) {
#pragma unroll
        for (int r = 0; r < 4; ++r) {
            float s = 0.f;
#pragma unroll
            for (int j = 0; j < 4; ++j) {
                float x = acc[i][j][r] + wqv[j] + ubv[j];
                x = fminf(fmaxf(x, -15.f), 15.f);
                float e = __expf(2.f * x);
                s += ((e - 1.f) / (e + 1.f)) * vw[j];
            }
#pragma unroll
            for (int o = 8; o >= 1; o >>= 1) s += __shfl_xor(s, o);
            if (col16 == 0) {
                const int rloc = wm * 64 + i * 16 + kg * 4 + r;
                const int m = (i256b + rloc) * 8 + jb;
                scores[(size_t)bh * NL + m] = s + vb0;
            }
        }
    }
}

// ---------------- Kernel 4: softmax -> dist (out) + attn = dist @ Kh ----------------
__global__ __launch_bounds__(256) void softmax_attn_kernel(
    const float* __restrict__ Km,
    const float* __restrict__ scores,
    float* __restrict__ out)  // [0,32768) attn, [32768,...) dist
{
    __shared__ float sd[NL];
    __shared__ float red[256];
    __shared__ float att[16][64];

    const int bh = blockIdx.x;
    const int b = bh >> 3, h = bh & 7;
    const int t = threadIdx.x;

    float loc[8];
    float mx = -1e30f;
#pragma unroll
    for (int j = 0; j < 8; ++j) {
        loc[j] = scores[(size_t)bh * NL + j * 256 + t];
        mx = fmaxf(mx, loc[j]);
    }
    red[t] = mx;
    __syncthreads();
    for (int s2 = 128; s2 > 0; s2 >>= 1) {
        if (t < s2) red[t] = fmaxf(red[t], red[t + s2]);
        __syncthreads();
    }
    mx = red[0];
    __syncthreads();
    float sum = 0.f;
#pragma unroll
    for (int j = 0; j < 8; ++j) {
        loc[j] = __expf(loc[j] - mx);
        sum += loc[j];
    }
    red[t] = sum;
    __syncthreads();
    for (int s2 = 128; s2 > 0; s2 >>= 1) {
        if (t < s2) red[t] += red[t + s2];
        __syncthreads();
    }
    const float inv = 1.f / red[0];
    __syncthreads();

    float* dist_out = out + 32768 + (size_t)bh * NL;
#pragma unroll
    for (int j = 0; j < 8; ++j) {
        float d = loc[j] * inv;
        sd[j * 256 + t] = d;
        dist_out[j * 256 + t] = d;
    }
    __syncthreads();

    const int wave = t >> 6, lane = t & 63;
    const int g = lane >> 4;
    const int c4 = (lane & 15) * 4;
    f32x4 acc = (f32x4){0.f, 0.f, 0.f, 0.f};
    const float* kb = Km + ((size_t)b * NL + h * 256) * ND;
    for (int rr = 0; rr < 16; ++rr) {
        const int row = wave * 64 + rr * 4 + g;
        const float* kr = kb + (size_t)row * ND;
#pragma unroll
        for (int jb2 = 0; jb2 < 8; ++jb2) {
            const float w = sd[row * 8 + jb2];
            float4 v = *(const float4*)(kr + jb2 * 64 + c4);
            acc[0] += w * v.x;
            acc[1] += w * v.y;
            acc[2] += w * v.z;
            acc[3] += w * v.w;
        }
    }
    *(f32x4*)&att[wave * 4 + g][c4] = acc;
    __syncthreads();
    if (t < 64) {
        float a = 0.f;
#pragma unroll
        for (int i = 0; i < 16; ++i) a += att[i][t];
        out[(size_t)b * ND + h * 64 + t] = a;
    }
}

extern "C" void kernel_launch(void* const* d_in, const int* in_sizes, int n_in,
                              void* d_out, int out_size, void* d_ws, size_t ws_size,
                              hipStream_t stream) {
    const float* Q  = (const float*)d_in[0];
    const float* Km = (const float*)d_in[1];
    const float* Ww = (const float*)d_in[2];
    const float* Wb = (const float*)d_in[3];
    const float* Uw = (const float*)d_in[4];
    const float* Ub = (const float*)d_in[5];
    const float* Vw = (const float*)d_in[6];
    const float* Vb = (const float*)d_in[7];
    float* out = (float*)d_out;

    char* ws = (char*)d_ws;
    float* scores = (float*)ws;                              // 4 MB
    float* Wq = (float*)(ws + 4194304);                      // 128 KB
    _Float16* UwH = (_Float16*)(ws + 4194304 + 131072);      // 512 KB

    wq_kernel<<<dim3(64), dim3(256), 0, stream>>>(Q, Ww, Wb, Wq);
    cvt_uw_kernel<<<dim3(256), dim3(256), 0, stream>>>(Uw, UwH);
    uk_score_kernel<<<dim3(4096), dim3(256), 0, stream>>>(Km, UwH, Ub, Wq, Vw, Vb, scores);
    softmax_attn_kernel<<<dim3(512), dim3(256), 0, stream>>>(Km, scores, out);
}